// Round 2
// 486.577 us; speedup vs baseline: 1.0461x; 1.0461x over previous
//
#include <hip/hip_runtime.h>
#include <hip/hip_bf16.h>
#include <math.h>

// MaskedSelfAttention: B=4, T=4096, D=1024, fp32 in/out, bf16 MFMA compute.
// R7: fixes R6's race — staged halves (rows 0-127 / 128-255) do NOT align
// with read quadrants (h=0 reads rows 0-63 AND 128-191 across waves), so
// A0 must be staged at P5 (after P3's h=1 read), not P2. Corrected stage
// order: P1/P2 buf1.A0/A1, P3/P4 buf0.B0/B1, P5/P6 buf0.A0/A1,
// P7/P8 buf1.B0/B1; counted VM4 at P4/P8. Core register-slimmed
// (precomputed lane offsets, epilogue recomputed after core) to keep
// VGPR<256 so no scratch ops corrupt the vmcnt accounting.

typedef __bf16 bf16;
typedef __bf16 bf16x8 __attribute__((ext_vector_type(8)));
typedef float  f32x4  __attribute__((ext_vector_type(4)));

#define LOG2E 1.4426950408889634f

// ---------------- ws layout (bytes) ----------------
static constexpr size_t OFF_XB   = 0;            // [16384][1024] bf16   33.5MB
static constexpr size_t OFF_WQB  = 33554432;     // [1024][1024] bf16
static constexpr size_t OFF_WKB  = 35651584;
static constexpr size_t OFF_WVB  = 37748736;
static constexpr size_t OFF_Q    = 39845888;     // [4][4096][1024] bf16
static constexpr size_t OFF_K    = 73400320;
static constexpr size_t OFF_VT   = 106954752;    // [4][1024][4096] bf16
static constexpr size_t OFF_S    = 140509184;    // [4][528 tri tiles][128*128] bf16  69MB
static constexpr size_t OFF_PSUM = 209715200;    // [4][4096][32] f32
static constexpr size_t OFF_LINV = 211812352;    // [16384] f32

// ---------------- helpers ----------------
typedef __attribute__((address_space(1))) void gvoid_t;
typedef __attribute__((address_space(3))) void lvoid_t;

__device__ __forceinline__ void gload16(const void* g, void* l) {
  __builtin_amdgcn_global_load_lds((gvoid_t*)g, (lvoid_t*)l, 16, 0, 0);
}

#define PRIO1() __builtin_amdgcn_s_setprio(1)
#define PRIO0() __builtin_amdgcn_s_setprio(0)
#define BAR()   __builtin_amdgcn_s_barrier()
#define LGKM0() asm volatile("s_waitcnt lgkmcnt(0)" ::: "memory")
#define LGKM8() asm volatile("s_waitcnt lgkmcnt(8)" ::: "memory")
#define VM0()   asm volatile("s_waitcnt vmcnt(0)" ::: "memory")
#define VM4()   asm volatile("s_waitcnt vmcnt(4)" ::: "memory")

// ======== 128x128 machinery (s_gemm / o_gemm) ========
struct Ctx { int tid, lane, quad, col16, wr, wc, wcol; };
__device__ __forceinline__ Ctx mk_ctx() {
  Ctx c; c.tid = (int)threadIdx.x; c.lane = c.tid & 63;
  int w = c.tid >> 6;
  c.quad = c.lane >> 4; c.col16 = c.lane & 15;
  c.wr = (w >> 1) * 64; c.wc = (w & 1) * 64; c.wcol = w & 1;
  return c;
}

// Stage a 128-row x 32-col bf16 tile (row stride ld elems) into s[128][32].
__device__ __forceinline__ void stage_tile(const bf16* g, long ld, bf16* s, int tid) {
  int lane = tid & 63, w = tid >> 6;
  const bf16* gp = g + (long)(lane >> 2) * ld + (long)(lane & 3) * 8;
  long step = 16 * ld;
  gload16(gp + (long)(2 * w) * step,     s + (2 * w) * 512);
  gload16(gp + (long)(2 * w + 1) * step, s + (2 * w + 1) * 512);
}

// One BK=32 sub-step: 8 ds_read_b128 + 16 MFMA per wave.
__device__ __forceinline__ void mfma_step(const bf16* sA, const bf16* sB,
                                          const Ctx& c, f32x4 acc[4][4]) {
  bf16x8 a[4], b[4];
#pragma unroll
  for (int i = 0; i < 4; ++i) {
    a[i] = *(const bf16x8*)(sA + ((c.wr + i * 16 + c.col16) * 32 + c.quad * 8));
    b[i] = *(const bf16x8*)(sB + ((c.wc + i * 16 + c.col16) * 32 + c.quad * 8));
  }
#pragma unroll
  for (int i = 0; i < 4; ++i)
#pragma unroll
    for (int j = 0; j < 4; ++j)
      acc[i][j] = __builtin_amdgcn_mfma_f32_16x16x32_bf16(a[i], b[j], acc[i][j], 0, 0, 0);
}

__device__ __forceinline__ void zero_acc(f32x4 acc[4][4]) {
  f32x4 z = {0.f, 0.f, 0.f, 0.f};
#pragma unroll
  for (int i = 0; i < 4; ++i)
#pragma unroll
    for (int j = 0; j < 4; ++j) acc[i][j] = z;
}

__device__ __forceinline__ int tridec(int i) {
  int qt = (int)((sqrtf(8.0f * (float)i + 1.0f) - 1.0f) * 0.5f);
  while ((qt + 1) * (qt + 2) / 2 <= i) ++qt;
  while (qt * (qt + 1) / 2 > i) --qt;
  return qt;
}

// ======== 256x256 8-phase machinery (qkv_gemm), ld = 1024 fixed ========
struct CC { int soff, raOff, rbOff, lofs; };
__device__ __forceinline__ CC mk_cc(int tid) {
  CC c;
  int lane = tid & 63, w = tid >> 6;
  int quad = lane >> 4, col16 = lane & 15;
  int wrow = (w >> 2) << 7, wcol = (w & 3) << 6;
  // staging: per-lane global offset (row*1024 + swizzled 8-elem chunk)
  c.soff = ((tid >> 3) << 10) + (((tid & 7) ^ (((tid >> 5) & 1) << 1)) << 3);
  // reads: swizzled column base (XOR elem-bit4 with row-bit2 = col16-bit2)
  int cS = (quad << 3) ^ (((col16 >> 2) & 1) << 4);
  c.raOff = ((wrow + col16) << 6) + cS;
  c.rbOff = ((wcol + col16) << 6) + cS;
  c.lofs = w << 9;
  return c;
}

// Stage one 128-row x 64-col half-tile (2x 16B per thread, linear LDS dest,
// swizzle pre-applied on the global source chunk).
__device__ __forceinline__ void stg(const bf16* g, int kofs, bf16* l, const CC& c) {
  const bf16* g0 = g + kofs + c.soff;
  gload16(g0,         l + c.lofs);
  gload16(g0 + 65536, l + c.lofs + 4096);  // +64 rows
}

// 8 ds_read_b128: A fragments for quadrant row-half h (rows wrow+h*64..+63).
__device__ __forceinline__ void read_a(const bf16* buf, const CC& c, int h, bf16x8 a[8]) {
#pragma unroll
  for (int f = 0; f < 4; ++f)
#pragma unroll
    for (int kk = 0; kk < 2; ++kk)
      a[f * 2 + kk] = *(const bf16x8*)(buf + c.raOff + h * 4096 + f * 1024 + kk * 32);
}

// 4 ds_read_b128: B fragments for quadrant col-half cc (cols wcol+cc*32..+31).
__device__ __forceinline__ void read_b(const bf16* buf, const CC& c, int cc, bf16x8 bb[4]) {
#pragma unroll
  for (int g = 0; g < 2; ++g)
#pragma unroll
    for (int kk = 0; kk < 2; ++kk)
      bb[g * 2 + kk] = *(const bf16x8*)(buf + c.rbOff + cc * 2048 + g * 1024 + kk * 32);
}

// 16 MFMA: one 64x32 C-quadrant x K=64.
__device__ __forceinline__ void mfma16(const bf16x8 a[8], const bf16x8 bb[4],
                                       int h, int cc, f32x4 acc[8][4]) {
#pragma unroll
  for (int f = 0; f < 4; ++f)
#pragma unroll
    for (int g = 0; g < 2; ++g)
#pragma unroll
      for (int kk = 0; kk < 2; ++kk)
        acc[h * 4 + f][cc * 2 + g] = __builtin_amdgcn_mfma_f32_16x16x32_bf16(
            a[f * 2 + kk], bb[g * 2 + kk], acc[h * 4 + f][cc * 2 + g], 0, 0, 0);
}

__device__ __forceinline__ void zero8x4(f32x4 acc[8][4]) {
  f32x4 z = {0.f, 0.f, 0.f, 0.f};
#pragma unroll
  for (int i = 0; i < 8; ++i)
#pragma unroll
    for (int j = 0; j < 4; ++j) acc[i][j] = z;
}

// 256x256 NT GEMM, K = NT*64 (NT even >= 4), ld = 1024 both operands.
// Stage slots: P1/P2 buf1.A0/A1(t=2i+1), P3/P4 buf0.B0/B1(t=2i+2),
// P5/P6 buf0.A0/A1(t=2i+2), P7/P8 buf1.B0/B1(t=2i+3).
// Region read-completion: buf A-halves after P3(buf0)/P7(buf1); B-halves
// after P2/P6 — every stage lands strictly after the last read of its region.
// vmcnt: 4 outstanding at iter entry; VM4@P4 -> t1 landed; VM4@P8 -> t2.
template <int NT>
__device__ __forceinline__ void gemm256_core(const bf16* __restrict__ Ag,
                                             const bf16* __restrict__ Bg,
                                             bf16* sA0, bf16* sA1,
                                             bf16* sB0, bf16* sB1,
                                             const CC& c, f32x4 acc[8][4]) {
  // prologue: tile0 full + tile1 B-halves; VM4 retires tile0's 8 loads.
  stg(Ag, 0,           sA0, c); stg(Ag, 131072,      sA0 + 8192, c);
  stg(Bg, 0,           sB0, c); stg(Bg, 131072,      sB0 + 8192, c);
  stg(Bg, 64,          sB1, c); stg(Bg, 64 + 131072, sB1 + 8192, c);
  VM4(); BAR();

  bf16x8 a[8], b0[4], b1[4];
#pragma unroll 1
  for (int i = 0; i < NT / 2 - 1; ++i) {
    const int k1 = (2 * i + 1) << 6, k2 = k1 + 64, k3 = k1 + 128;
    // P1: read buf0 (h0, cc0) ; stage buf1.A0 (t1)
    read_a(sA0, c, 0, a); read_b(sB0, c, 0, b0);
    stg(Ag, k1, sA1, c);
    LGKM8(); BAR(); LGKM0();
    PRIO1(); mfma16(a, b0, 0, 0, acc); PRIO0(); BAR();
    // P2: read buf0 cc1 ; stage buf1.A1 (t1)
    read_b(sB0, c, 1, b1);
    stg(Ag, k1 + 131072, sA1 + 8192, c);
    BAR(); LGKM0();
    PRIO1(); mfma16(a, b1, 0, 1, acc); PRIO0(); BAR();
    // P3: read buf0 h1 ; stage buf0.B0 (t2; buf0 B-reads done at P2)
    read_a(sA0, c, 1, a);
    stg(Bg, k2, sB0, c);
    BAR(); LGKM0();
    PRIO1(); mfma16(a, b1, 1, 1, acc); PRIO0(); BAR();
    // P4: stage buf0.B1 (t2) ; VM4 -> t1 fully landed
    stg(Bg, k2 + 131072, sB0 + 8192, c);
    BAR();
    PRIO1(); mfma16(a, b0, 1, 0, acc); PRIO0();
    VM4(); BAR();
    // P5: read buf1 (h0, cc0) ; stage buf0.A0 (t2; buf0 A-reads done at P3)
    read_a(sA1, c, 0, a); read_b(sB1, c, 0, b0);
    stg(Ag, k2, sA0, c);
    LGKM8(); BAR(); LGKM0();
    PRIO1(); mfma16(a, b0, 0, 0, acc); PRIO0(); BAR();
    // P6: read buf1 cc1 ; stage buf0.A1 (t2)
    read_b(sB1, c, 1, b1);
    stg(Ag, k2 + 131072, sA0 + 8192, c);
    BAR(); LGKM0();
    PRIO1(); mfma16(a, b1, 0, 1, acc); PRIO0(); BAR();
    // P7: read buf1 h1 ; stage buf1.B0 (t3; buf1 B-reads done at P6)
    read_a(sA1, c, 1, a);
    stg(Bg, k3, sB1, c);
    BAR(); LGKM0();
    PRIO1(); mfma16(a, b1, 1, 1, acc); PRIO0(); BAR();
    // P8: stage buf1.B1 (t3) ; VM4 -> t2 fully landed
    stg(Bg, k3 + 131072, sB1 + 8192, c);
    BAR();
    PRIO1(); mfma16(a, b0, 1, 0, acc); PRIO0();
    VM4(); BAR();
  }
  // peeled final pair: t = NT-2 (buf0), NT-1 (buf1); stage only t1's A-halves.
  {
    const int k1 = (NT - 1) << 6;
    read_a(sA0, c, 0, a); read_b(sB0, c, 0, b0);
    stg(Ag, k1, sA1, c);
    LGKM8(); BAR(); LGKM0();
    PRIO1(); mfma16(a, b0, 0, 0, acc); PRIO0(); BAR();
    read_b(sB0, c, 1, b1);
    stg(Ag, k1 + 131072, sA1 + 8192, c);
    BAR(); LGKM0();
    PRIO1(); mfma16(a, b1, 0, 1, acc); PRIO0(); BAR();
    read_a(sA0, c, 1, a);
    BAR(); LGKM0();
    PRIO1(); mfma16(a, b1, 1, 1, acc); PRIO0(); BAR();
    BAR();
    PRIO1(); mfma16(a, b0, 1, 0, acc); PRIO0();
    VM0(); BAR();
    read_a(sA1, c, 0, a); read_b(sB1, c, 0, b0);
    LGKM8(); BAR(); LGKM0();
    PRIO1(); mfma16(a, b0, 0, 0, acc); PRIO0(); BAR();
    read_b(sB1, c, 1, b1);
    BAR(); LGKM0();
    PRIO1(); mfma16(a, b1, 0, 1, acc); PRIO0(); BAR();
    read_a(sA1, c, 1, a);
    BAR(); LGKM0();
    PRIO1(); mfma16(a, b1, 1, 1, acc); PRIO0();
    mfma16(a, b0, 1, 0, acc);  // epilogue touches no LDS; no trailing barrier
  }
}

// ---------------- kernels ----------------

// All four fp32->bf16 conversions in one dispatch.
__global__ __launch_bounds__(256) void cvt_all(const float* __restrict__ x,
                                               const float* __restrict__ Wq,
                                               const float* __restrict__ Wk,
                                               const float* __restrict__ Wv,
                                               bf16* __restrict__ xb,
                                               bf16* __restrict__ wqb,
                                               bf16* __restrict__ wkb,
                                               bf16* __restrict__ wvb) {
  int b = (int)blockIdx.x;
  const float* in; bf16* out; long base;
  if (b < 8192)      { in = x;  out = xb;  base = (long)b * 2048; }
  else if (b < 8704) { in = Wq; out = wqb; base = (long)(b - 8192) * 2048; }
  else if (b < 9216) { in = Wk; out = wkb; base = (long)(b - 8704) * 2048; }
  else               { in = Wv; out = wvb; base = (long)(b - 9216) * 2048; }
  long i = base + (long)threadIdx.x * 8;
  float4 f0 = *(const float4*)(in + i);
  float4 f1 = *(const float4*)(in + i + 4);
  bf16x8 h;
  h[0] = (bf16)f0.x; h[1] = (bf16)f0.y; h[2] = (bf16)f0.z; h[3] = (bf16)f0.w;
  h[4] = (bf16)f1.x; h[5] = (bf16)f1.y; h[6] = (bf16)f1.z; h[7] = (bf16)f1.w;
  *(bf16x8*)(out + i) = h;
}

// Merged projections, 256x256 tiles, 8-phase core. 768 blocks x 512 threads.
// ids [0,256): Q  [256,512): K  [512,768): Vt.  XCD-swizzled (768 = 8*96).
__global__ __launch_bounds__(512, 2) void qkv_gemm(const bf16* __restrict__ X,
                                                   const bf16* __restrict__ Wq,
                                                   const bf16* __restrict__ Wk,
                                                   const bf16* __restrict__ Wv,
                                                   const float* __restrict__ bq,
                                                   const float* __restrict__ bk,
                                                   const float* __restrict__ bv,
                                                   bf16* __restrict__ Q,
                                                   bf16* __restrict__ K,
                                                   bf16* __restrict__ Vt) {
  __shared__ __align__(16) bf16 lds[4][16384];  // sA0,sA1,sB0,sB1 = 128 KiB
  const int tid = (int)threadIdx.x;
  const CC c = mk_cc(tid);
  int b0i = (int)blockIdx.x;
  int b = (b0i & 7) * 96 + (b0i >> 3);  // bijective XCD swizzle
  const bf16 *Ag, *Bg;
  const bool is_vt = (b >= 512);
  if (!is_vt) {
    int isK = b >> 8, rem = b & 255;
    Ag = X + (long)(rem >> 2) * 262144;                 // t-row base * 1024
    Bg = (isK ? Wk : Wq) + (long)(rem & 3) * 262144;    // e-col base * 1024
  } else {
    int rem = b - 512;
    Ag = Wv + (long)((rem >> 4) & 3) * 262144;          // e rows of Vt
    Bg = X + (long)(rem >> 6) * 4194304 + (long)(rem & 15) * 262144;  // t cols
  }
  f32x4 acc[8][4];
  zero8x4(acc);
  gemm256_core<16>(Ag, Bg, lds[0], lds[1], lds[2], lds[3], c, acc);

  // epilogue: recompute all indices (keeps core register-light)
  const int lane = tid & 63, w = tid >> 6;
  const int quad = lane >> 4, col16 = lane & 15;
  const int wrow = (w >> 2) << 7, wcol = (w & 3) << 6;
  if (!is_vt) {
    int isK = b >> 8, rem = b & 255;
    long r0 = (long)(rem >> 2) * 256, c0 = (long)(rem & 3) * 256;
    const float* bias = isK ? bk : bq;
    bf16* out = isK ? K : Q;
#pragma unroll
    for (int n = 0; n < 4; ++n) {
      int col = (int)c0 + wcol + (n >> 1) * 32 + (n & 1) * 16 + col16;
      float bb = bias[col];
#pragma unroll
      for (int m = 0; m < 8; ++m) {
        long rowb = r0 + wrow + (m >> 2) * 64 + (m & 3) * 16 + quad * 4;
#pragma unroll
        for (int r = 0; r < 4; ++r)
          out[(rowb + r) * 1024 + col] = (bf16)(acc[m][n][r] + bb);
      }
    }
  } else {
    int rem = b - 512;
    int z = rem >> 6;
    long r0 = (long)((rem >> 4) & 3) * 256, c0 = (long)(rem & 15) * 256;
    bf16* out = Vt + (long)z * 4194304;
#pragma unroll
    for (int m = 0; m < 8; ++m) {
      long rowb = r0 + wrow + (m >> 2) * 64 + (m & 3) * 16 + quad * 4;
      float bb[4];
#pragma unroll
      for (int r = 0; r < 4; ++r) bb[r] = bv[rowb + r];
#pragma unroll
      for (int n = 0; n < 4; ++n) {
        int col = (int)c0 + wcol + (n >> 1) * 32 + (n & 1) * 16 + col16;
#pragma unroll
        for (int r = 0; r < 4; ++r)
          out[(rowb + r) * 4096 + col] = (bf16)(acc[m][n][r] + bb[r]);
      }
    }
  }
}

// P~ = exp(Q.K^T/32) (masked entries = 0) on lower-tri 128x128 tiles; BK=64.
// Also emits per-(row, k-tile) sums of the ROUNDED bf16 values -> psum.
__global__ __launch_bounds__(256) void s_gemm(const bf16* __restrict__ Q,
                                              const bf16* __restrict__ K,
                                              bf16* __restrict__ S,
                                              float* __restrict__ psum) {
  __shared__ __align__(16) bf16 sA[2][128 * 32], sB[2][128 * 32];
  __shared__ float sred[2][128];
  Ctx c = mk_ctx();
  int ti = blockIdx.x, z = blockIdx.z;
  int qt = tridec(ti);
  int kt = ti - qt * (qt + 1) / 2;
  long q0 = (long)qt * 128, k0 = (long)kt * 128;
  const bf16* Ab = Q + (long)z * 4194304 + q0 * 1024;
  const bf16* Bb = K + (long)z * 4194304 + k0 * 1024;
  f32x4 acc[4][4]; zero_acc(acc);
  for (int k = 0; k < 1024; k += 64) {
    stage_tile(Ab + k,      1024, sA[0], c.tid);
    stage_tile(Ab + k + 32, 1024, sA[1], c.tid);
    stage_tile(Bb + k,      1024, sB[0], c.tid);
    stage_tile(Bb + k + 32, 1024, sB[1], c.tid);
    __syncthreads();
    mfma_step(sA[0], sB[0], c, acc);
    mfma_step(sA[1], sB[1], c, acc);
    __syncthreads();
  }
  bf16* st = S + ((long)z * 528 + ti) * 16384;
  const bool diag = (qt == kt);
  float rs[4][4];
#pragma unroll
  for (int i = 0; i < 4; ++i) {
#pragma unroll
    for (int r = 0; r < 4; ++r) {
      int row_l = c.wr + i * 16 + c.quad * 4 + r;
      float s = 0.f;
#pragma unroll
      for (int j = 0; j < 4; ++j) {
        int col_l = c.wc + j * 16 + c.col16;
        float p = exp2f(acc[i][j][r] * (0.03125f * LOG2E));
        if (diag && col_l > row_l) p = 0.0f;
        bf16 h = (bf16)p;
        st[row_l * 128 + col_l] = h;
        s += (float)h;  // sum rounded values for exact consistency with PV
      }
      rs[i][r] = s;
    }
  }
#pragma unroll
  for (int i = 0; i < 4; ++i)
#pragma unroll
    for (int r = 0; r < 4; ++r)
#pragma unroll
      for (int m = 1; m <= 8; m <<= 1)
        rs[i][r] += __shfl_xor(rs[i][r], m);
  if (c.col16 == 0) {
#pragma unroll
    for (int i = 0; i < 4; ++i)
#pragma unroll
      for (int r = 0; r < 4; ++r)
        sred[c.wcol][c.wr + i * 16 + c.quad * 4 + r] = rs[i][r];
  }
  __syncthreads();
  if (c.tid < 128)
    psum[((long)z * 4096 + q0 + c.tid) * 32 + kt] = sred[0][c.tid] + sred[1][c.tid];
}

// linv[row] = 1 / sum over causal k-tiles of psum
__global__ __launch_bounds__(256) void inv_sums(const float* __restrict__ psum,
                                                float* __restrict__ linv) {
  long i = (long)blockIdx.x * 256 + threadIdx.x;  // 16384 rows
  int q = (int)(i & 4095);
  int nt = (q >> 7) + 1;
  const float* ps = psum + i * 32;
  float l = 0.f;
  for (int t = 0; t < nt; ++t) l += ps[t];
  linv[i] = 1.0f / l;
}

// O[q][e] = (sum_k P~[q][k] * Vt[e][k]) * linv[q], causal k bound; fp32 out.
// 1D grid: z bits 0-1, et bits 2-4, q0 bits 5-7, gen bits 8-9.
// qt = {q0, 15-q0, 16+q0, 31-q0} by gen -> co-resident set on each CU
// (blocks c, c+256, c+512, c+768) sums to exactly 66 k-tiles.
__global__ __launch_bounds__(256) void o_gemm(const bf16* __restrict__ S,
                                              const bf16* __restrict__ Vt,
                                              const float* __restrict__ linv,
                                              float* __restrict__ out) {
  __shared__ __align__(16) bf16 sA[2][128 * 32], sB[2][128 * 32];
  Ctx c = mk_ctx();
  int b = (int)blockIdx.x;
  int z = b & 3, et = (b >> 2) & 7, q0i = (b >> 5) & 7, gen = b >> 8;
  int qt = (gen == 0) ? q0i : (gen == 1) ? 15 - q0i
         : (gen == 2) ? 16 + q0i : 31 - q0i;
  long q0 = (long)qt * 128, e0 = (long)et * 128;
  const bf16* Bb = Vt + (long)z * 4194304 + e0 * 4096;
  long tribase = ((long)z * 528 + (long)qt * (qt + 1) / 2) * 16384;
  f32x4 acc[4][4]; zero_acc(acc);
  int kend = (qt + 1) * 128;
  for (int k = 0; k < kend; k += 64) {
    const bf16* Ab = S + tribase + (long)(k >> 7) * 16384 + (k & 127);
    stage_tile(Ab,      128, sA[0], c.tid);
    stage_tile(Ab + 32, 128, sA[1], c.tid);
    stage_tile(Bb + k,      4096, sB[0], c.tid);
    stage_tile(Bb + k + 32, 4096, sB[1], c.tid);
    __syncthreads();
    mfma_step(sA[0], sB[0], c, acc);
    mfma_step(sA[1], sB[1], c, acc);
    __syncthreads();
  }
  long zq = (long)z * 4096 + q0;
#pragma unroll
  for (int i = 0; i < 4; ++i) {
    int rowb = c.wr + i * 16 + c.quad * 4;
    float li[4];
#pragma unroll
    for (int r = 0; r < 4; ++r) li[r] = linv[zq + rowb + r];
#pragma unroll
    for (int j = 0; j < 4; ++j) {
      int col = c.wc + j * 16 + c.col16;
#pragma unroll
      for (int r = 0; r < 4; ++r)
        out[(zq + rowb + r) * 1024 + e0 + col] = acc[i][j][r] * li[r];
    }
  }
}

// ---------------- launcher ----------------
extern "C" void kernel_launch(void* const* d_in, const int* in_sizes, int n_in,
                              void* d_out, int out_size, void* d_ws, size_t ws_size,
                              hipStream_t stream) {
  (void)in_sizes; (void)n_in; (void)out_size; (void)ws_size;
  const float* x  = (const float*)d_in[0];
  const float* Wq = (const float*)d_in[1];
  const float* bq = (const float*)d_in[2];
  const float* Wk = (const float*)d_in[3];
  const float* bk = (const float*)d_in[4];
  const float* Wv = (const float*)d_in[5];
  const float* bv = (const float*)d_in[6];

  char* ws = (char*)d_ws;
  bf16*  xb   = (bf16*)(ws + OFF_XB);
  bf16*  wqb  = (bf16*)(ws + OFF_WQB);
  bf16*  wkb  = (bf16*)(ws + OFF_WKB);
  bf16*  wvb  = (bf16*)(ws + OFF_WVB);
  bf16*  Qb   = (bf16*)(ws + OFF_Q);
  bf16*  Kb   = (bf16*)(ws + OFF_K);
  bf16*  Vtb  = (bf16*)(ws + OFF_VT);
  bf16*  Sb   = (bf16*)(ws + OFF_S);
  float* psum = (float*)(ws + OFF_PSUM);
  float* linv = (float*)(ws + OFF_LINV);

  cvt_all<<<9728, 256, 0, stream>>>(x, Wq, Wk, Wv, xb, wqb, wkb, wvb);
  qkv_gemm<<<768, 512, 0, stream>>>(xb, wqb, wkb, wvb, bq, bk, bv, Qb, Kb, Vtb);
  s_gemm<<<dim3(528, 1, 4), 256, 0, stream>>>(Qb, Kb, Sb, psum);
  inv_sums<<<64, 256, 0, stream>>>(psum, linv);
  o_gemm<<<1024, 256, 0, stream>>>(Sb, Vtb, linv, (float*)d_out);
}

// Round 3
// 485.650 us; speedup vs baseline: 1.0481x; 1.0019x over previous
//
#include <hip/hip_runtime.h>
#include <hip/hip_bf16.h>
#include <math.h>

// MaskedSelfAttention: B=4, T=4096, D=1024, fp32 in/out, bf16 MFMA compute.
// R8: (1) full 3-bit LDS XOR swizzle (slot = chunk ^ (row&7)) — R7's 1-bit
// version left a 2x LDS-read serialization (banks 0-15 only). kk-dependent
// XOR handled by TWO per-lane read bases (ra0/ra1, rb0/rb1) so immediates
// stay compile-time. (2) s_gemm ported onto the verified gemm256_core
// (256x256 8-phase, 136 tri-tiles x 4z = 544 blocks); epilogue splits into
// four 128x128 quadrants of the existing S layout, bit-identical psum.

typedef __bf16 bf16;
typedef __bf16 bf16x8 __attribute__((ext_vector_type(8)));
typedef float  f32x4  __attribute__((ext_vector_type(4)));

#define LOG2E 1.4426950408889634f

// ---------------- ws layout (bytes) ----------------
static constexpr size_t OFF_XB   = 0;            // [16384][1024] bf16   33.5MB
static constexpr size_t OFF_WQB  = 33554432;     // [1024][1024] bf16
static constexpr size_t OFF_WKB  = 35651584;
static constexpr size_t OFF_WVB  = 37748736;
static constexpr size_t OFF_Q    = 39845888;     // [4][4096][1024] bf16
static constexpr size_t OFF_K    = 73400320;
static constexpr size_t OFF_VT   = 106954752;    // [4][1024][4096] bf16
static constexpr size_t OFF_S    = 140509184;    // [4][528 tri tiles][128*128] bf16  69MB
static constexpr size_t OFF_PSUM = 209715200;    // [4][4096][32] f32
static constexpr size_t OFF_LINV = 211812352;    // [16384] f32

// ---------------- helpers ----------------
typedef __attribute__((address_space(1))) void gvoid_t;
typedef __attribute__((address_space(3))) void lvoid_t;

__device__ __forceinline__ void gload16(const void* g, void* l) {
  __builtin_amdgcn_global_load_lds((gvoid_t*)g, (lvoid_t*)l, 16, 0, 0);
}

#define PRIO1() __builtin_amdgcn_s_setprio(1)
#define PRIO0() __builtin_amdgcn_s_setprio(0)
#define BAR()   __builtin_amdgcn_s_barrier()
#define LGKM0() asm volatile("s_waitcnt lgkmcnt(0)" ::: "memory")
#define LGKM8() asm volatile("s_waitcnt lgkmcnt(8)" ::: "memory")
#define VM0()   asm volatile("s_waitcnt vmcnt(0)" ::: "memory")
#define VM4()   asm volatile("s_waitcnt vmcnt(4)" ::: "memory")

// ======== 128x128 machinery (o_gemm) ========
struct Ctx { int tid, lane, quad, col16, wr, wc, wcol; };
__device__ __forceinline__ Ctx mk_ctx() {
  Ctx c; c.tid = (int)threadIdx.x; c.lane = c.tid & 63;
  int w = c.tid >> 6;
  c.quad = c.lane >> 4; c.col16 = c.lane & 15;
  c.wr = (w >> 1) * 64; c.wc = (w & 1) * 64; c.wcol = w & 1;
  return c;
}

// Stage a 128-row x 32-col bf16 tile (row stride ld elems) into s[128][32].
__device__ __forceinline__ void stage_tile(const bf16* g, long ld, bf16* s, int tid) {
  int lane = tid & 63, w = tid >> 6;
  const bf16* gp = g + (long)(lane >> 2) * ld + (long)(lane & 3) * 8;
  long step = 16 * ld;
  gload16(gp + (long)(2 * w) * step,     s + (2 * w) * 512);
  gload16(gp + (long)(2 * w + 1) * step, s + (2 * w + 1) * 512);
}

// One BK=32 sub-step: 8 ds_read_b128 + 16 MFMA per wave.
__device__ __forceinline__ void mfma_step(const bf16* sA, const bf16* sB,
                                          const Ctx& c, f32x4 acc[4][4]) {
  bf16x8 a[4], b[4];
#pragma unroll
  for (int i = 0; i < 4; ++i) {
    a[i] = *(const bf16x8*)(sA + ((c.wr + i * 16 + c.col16) * 32 + c.quad * 8));
    b[i] = *(const bf16x8*)(sB + ((c.wc + i * 16 + c.col16) * 32 + c.quad * 8));
  }
#pragma unroll
  for (int i = 0; i < 4; ++i)
#pragma unroll
    for (int j = 0; j < 4; ++j)
      acc[i][j] = __builtin_amdgcn_mfma_f32_16x16x32_bf16(a[i], b[j], acc[i][j], 0, 0, 0);
}

__device__ __forceinline__ void zero_acc(f32x4 acc[4][4]) {
  f32x4 z = {0.f, 0.f, 0.f, 0.f};
#pragma unroll
  for (int i = 0; i < 4; ++i)
#pragma unroll
    for (int j = 0; j < 4; ++j) acc[i][j] = z;
}

__device__ __forceinline__ int tridec(int i) {
  int qt = (int)((sqrtf(8.0f * (float)i + 1.0f) - 1.0f) * 0.5f);
  while ((qt + 1) * (qt + 2) / 2 <= i) ++qt;
  while (qt * (qt + 1) / 2 > i) --qt;
  return qt;
}

// ======== 256x256 8-phase machinery (qkv_gemm, s_gemm), ld = 1024 ========
// LDS half-tile layout: [128 rows][8 slots of 16B]; slot s of row r holds
// global 16B-chunk s ^ (r&7). Reads: logical chunk (kk*4+quad) of row
// (..+col16) -> phys slot (kk*4+quad) ^ (col16&7). Per ds_read_b128 the 64
// lanes cover each of the 8 slot positions twice -> minimal 8 cyc, no
// extra bank conflicts. kk-dependent XOR folded into two bases ra0/ra1.
struct CC { int soff, ra0, ra1, rb0, rb1, lofs; };
__device__ __forceinline__ CC mk_cc(int tid) {
  CC c;
  int lane = tid & 63, w = tid >> 6;
  int quad = lane >> 4, col16 = lane & 15;
  int wrow = (w >> 2) << 7, wcol = (w & 3) << 6;
  int c7 = col16 & 7;
  c.soff = ((tid >> 3) << 10) + (((tid & 7) ^ ((tid >> 3) & 7)) << 3);
  c.ra0 = ((wrow + col16) << 6) + ((quad ^ c7) << 3);
  c.ra1 = ((wrow + col16) << 6) + (((4 | quad) ^ c7) << 3);
  c.rb0 = ((wcol + col16) << 6) + ((quad ^ c7) << 3);
  c.rb1 = ((wcol + col16) << 6) + (((4 | quad) ^ c7) << 3);
  c.lofs = w << 9;
  return c;
}

// Stage one 128-row x 64-col half-tile (2x 16B per thread, linear LDS dest,
// swizzle pre-applied on the global source chunk).
__device__ __forceinline__ void stg(const bf16* g, int kofs, bf16* l, const CC& c) {
  const bf16* g0 = g + kofs + c.soff;
  gload16(g0,         l + c.lofs);
  gload16(g0 + 65536, l + c.lofs + 4096);  // +64 rows
}

// 8 ds_read_b128: A fragments for quadrant row-half h (rows wrow+h*64..+63).
__device__ __forceinline__ void read_a(const bf16* buf, const CC& c, int h, bf16x8 a[8]) {
#pragma unroll
  for (int f = 0; f < 4; ++f) {
    a[f * 2 + 0] = *(const bf16x8*)(buf + c.ra0 + h * 4096 + f * 1024);
    a[f * 2 + 1] = *(const bf16x8*)(buf + c.ra1 + h * 4096 + f * 1024);
  }
}

// 4 ds_read_b128: B fragments for quadrant col-half cc (cols wcol+cc*32..+31).
__device__ __forceinline__ void read_b(const bf16* buf, const CC& c, int cc, bf16x8 bb[4]) {
#pragma unroll
  for (int g = 0; g < 2; ++g) {
    bb[g * 2 + 0] = *(const bf16x8*)(buf + c.rb0 + cc * 2048 + g * 1024);
    bb[g * 2 + 1] = *(const bf16x8*)(buf + c.rb1 + cc * 2048 + g * 1024);
  }
}

// 16 MFMA: one 64x32 C-quadrant x K=64.
__device__ __forceinline__ void mfma16(const bf16x8 a[8], const bf16x8 bb[4],
                                       int h, int cc, f32x4 acc[8][4]) {
#pragma unroll
  for (int f = 0; f < 4; ++f)
#pragma unroll
    for (int g = 0; g < 2; ++g)
#pragma unroll
      for (int kk = 0; kk < 2; ++kk)
        acc[h * 4 + f][cc * 2 + g] = __builtin_amdgcn_mfma_f32_16x16x32_bf16(
            a[f * 2 + kk], bb[g * 2 + kk], acc[h * 4 + f][cc * 2 + g], 0, 0, 0);
}

__device__ __forceinline__ void zero8x4(f32x4 acc[8][4]) {
  f32x4 z = {0.f, 0.f, 0.f, 0.f};
#pragma unroll
  for (int i = 0; i < 8; ++i)
#pragma unroll
    for (int j = 0; j < 4; ++j) acc[i][j] = z;
}

// 256x256 NT GEMM, K = NT*64 (NT even >= 4), ld = 1024 both operands.
// Stage slots: P1/P2 buf1.A0/A1(t=2i+1), P3/P4 buf0.B0/B1(t=2i+2),
// P5/P6 buf0.A0/A1(t=2i+2), P7/P8 buf1.B0/B1(t=2i+3).
// Region read-completion: buf A-halves after P3(buf0)/P7(buf1); B-halves
// after P2/P6 — every stage lands strictly after the last read of its region.
// vmcnt: 4 outstanding at iter entry; VM4@P4 -> t1 landed; VM4@P8 -> t2.
template <int NT>
__device__ __forceinline__ void gemm256_core(const bf16* __restrict__ Ag,
                                             const bf16* __restrict__ Bg,
                                             bf16* sA0, bf16* sA1,
                                             bf16* sB0, bf16* sB1,
                                             const CC& c, f32x4 acc[8][4]) {
  // prologue: tile0 full + tile1 B-halves; VM4 retires tile0's 8 loads.
  stg(Ag, 0,           sA0, c); stg(Ag, 131072,      sA0 + 8192, c);
  stg(Bg, 0,           sB0, c); stg(Bg, 131072,      sB0 + 8192, c);
  stg(Bg, 64,          sB1, c); stg(Bg, 64 + 131072, sB1 + 8192, c);
  VM4(); BAR();

  bf16x8 a[8], b0[4], b1[4];
#pragma unroll 1
  for (int i = 0; i < NT / 2 - 1; ++i) {
    const int k1 = (2 * i + 1) << 6, k2 = k1 + 64, k3 = k1 + 128;
    // P1: read buf0 (h0, cc0) ; stage buf1.A0 (t1)
    read_a(sA0, c, 0, a); read_b(sB0, c, 0, b0);
    stg(Ag, k1, sA1, c);
    LGKM8(); BAR(); LGKM0();
    PRIO1(); mfma16(a, b0, 0, 0, acc); PRIO0(); BAR();
    // P2: read buf0 cc1 ; stage buf1.A1 (t1)
    read_b(sB0, c, 1, b1);
    stg(Ag, k1 + 131072, sA1 + 8192, c);
    BAR(); LGKM0();
    PRIO1(); mfma16(a, b1, 0, 1, acc); PRIO0(); BAR();
    // P3: read buf0 h1 ; stage buf0.B0 (t2; buf0 B-reads done at P2)
    read_a(sA0, c, 1, a);
    stg(Bg, k2, sB0, c);
    BAR(); LGKM0();
    PRIO1(); mfma16(a, b1, 1, 1, acc); PRIO0(); BAR();
    // P4: stage buf0.B1 (t2) ; VM4 -> t1 fully landed
    stg(Bg, k2 + 131072, sB0 + 8192, c);
    BAR();
    PRIO1(); mfma16(a, b0, 1, 0, acc); PRIO0();
    VM4(); BAR();
    // P5: read buf1 (h0, cc0) ; stage buf0.A0 (t2; buf0 A-reads done at P3)
    read_a(sA1, c, 0, a); read_b(sB1, c, 0, b0);
    stg(Ag, k2, sA0, c);
    LGKM8(); BAR(); LGKM0();
    PRIO1(); mfma16(a, b0, 0, 0, acc); PRIO0(); BAR();
    // P6: read buf1 cc1 ; stage buf0.A1 (t2)
    read_b(sB1, c, 1, b1);
    stg(Ag, k2 + 131072, sA0 + 8192, c);
    BAR(); LGKM0();
    PRIO1(); mfma16(a, b1, 0, 1, acc); PRIO0(); BAR();
    // P7: read buf1 h1 ; stage buf1.B0 (t3; buf1 B-reads done at P6)
    read_a(sA1, c, 1, a);
    stg(Bg, k3, sB1, c);
    BAR(); LGKM0();
    PRIO1(); mfma16(a, b1, 1, 1, acc); PRIO0(); BAR();
    // P8: stage buf1.B1 (t3) ; VM4 -> t2 fully landed
    stg(Bg, k3 + 131072, sB1 + 8192, c);
    BAR();
    PRIO1(); mfma16(a, b0, 1, 0, acc); PRIO0();
    VM4(); BAR();
  }
  // peeled final pair: t = NT-2 (buf0), NT-1 (buf1); stage only t1's A-halves.
  {
    const int k1 = (NT - 1) << 6;
    read_a(sA0, c, 0, a); read_b(sB0, c, 0, b0);
    stg(Ag, k1, sA1, c);
    LGKM8(); BAR(); LGKM0();
    PRIO1(); mfma16(a, b0, 0, 0, acc); PRIO0(); BAR();
    read_b(sB0, c, 1, b1);
    stg(Ag, k1 + 131072, sA1 + 8192, c);
    BAR(); LGKM0();
    PRIO1(); mfma16(a, b1, 0, 1, acc); PRIO0(); BAR();
    read_a(sA0, c, 1, a);
    BAR(); LGKM0();
    PRIO1(); mfma16(a, b1, 1, 1, acc); PRIO0(); BAR();
    BAR();
    PRIO1(); mfma16(a, b0, 1, 0, acc); PRIO0();
    VM0(); BAR();
    read_a(sA1, c, 0, a); read_b(sB1, c, 0, b0);
    LGKM8(); BAR(); LGKM0();
    PRIO1(); mfma16(a, b0, 0, 0, acc); PRIO0(); BAR();
    read_b(sB1, c, 1, b1);
    BAR(); LGKM0();
    PRIO1(); mfma16(a, b1, 0, 1, acc); PRIO0(); BAR();
    read_a(sA1, c, 1, a);
    BAR(); LGKM0();
    PRIO1(); mfma16(a, b1, 1, 1, acc); PRIO0();
    mfma16(a, b0, 1, 0, acc);  // epilogue touches no staging LDS
  }
}

// ---------------- kernels ----------------

// All four fp32->bf16 conversions in one dispatch.
__global__ __launch_bounds__(256) void cvt_all(const float* __restrict__ x,
                                               const float* __restrict__ Wq,
                                               const float* __restrict__ Wk,
                                               const float* __restrict__ Wv,
                                               bf16* __restrict__ xb,
                                               bf16* __restrict__ wqb,
                                               bf16* __restrict__ wkb,
                                               bf16* __restrict__ wvb) {
  int b = (int)blockIdx.x;
  const float* in; bf16* out; long base;
  if (b < 8192)      { in = x;  out = xb;  base = (long)b * 2048; }
  else if (b < 8704) { in = Wq; out = wqb; base = (long)(b - 8192) * 2048; }
  else if (b < 9216) { in = Wk; out = wkb; base = (long)(b - 8704) * 2048; }
  else               { in = Wv; out = wvb; base = (long)(b - 9216) * 2048; }
  long i = base + (long)threadIdx.x * 8;
  float4 f0 = *(const float4*)(in + i);
  float4 f1 = *(const float4*)(in + i + 4);
  bf16x8 h;
  h[0] = (bf16)f0.x; h[1] = (bf16)f0.y; h[2] = (bf16)f0.z; h[3] = (bf16)f0.w;
  h[4] = (bf16)f1.x; h[5] = (bf16)f1.y; h[6] = (bf16)f1.z; h[7] = (bf16)f1.w;
  *(bf16x8*)(out + i) = h;
}

// Merged projections, 256x256 tiles, 8-phase core. 768 blocks x 512 threads.
// ids [0,256): Q  [256,512): K  [512,768): Vt.  XCD-swizzled (768 = 8*96).
__global__ __launch_bounds__(512, 2) void qkv_gemm(const bf16* __restrict__ X,
                                                   const bf16* __restrict__ Wq,
                                                   const bf16* __restrict__ Wk,
                                                   const bf16* __restrict__ Wv,
                                                   const float* __restrict__ bq,
                                                   const float* __restrict__ bk,
                                                   const float* __restrict__ bv,
                                                   bf16* __restrict__ Q,
                                                   bf16* __restrict__ K,
                                                   bf16* __restrict__ Vt) {
  __shared__ __align__(16) bf16 lds[4][16384];  // sA0,sA1,sB0,sB1 = 128 KiB
  const int tid = (int)threadIdx.x;
  const CC c = mk_cc(tid);
  int b0i = (int)blockIdx.x;
  int b = (b0i & 7) * 96 + (b0i >> 3);  // bijective XCD swizzle
  const bf16 *Ag, *Bg;
  const bool is_vt = (b >= 512);
  if (!is_vt) {
    int isK = b >> 8, rem = b & 255;
    Ag = X + (long)(rem >> 2) * 262144;                 // t-row base * 1024
    Bg = (isK ? Wk : Wq) + (long)(rem & 3) * 262144;    // e-col base * 1024
  } else {
    int rem = b - 512;
    Ag = Wv + (long)((rem >> 4) & 3) * 262144;          // e rows of Vt
    Bg = X + (long)(rem >> 6) * 4194304 + (long)(rem & 15) * 262144;  // t cols
  }
  f32x4 acc[8][4];
  zero8x4(acc);
  gemm256_core<16>(Ag, Bg, lds[0], lds[1], lds[2], lds[3], c, acc);

  // epilogue: recompute all indices (keeps core register-light)
  const int lane = tid & 63, w = tid >> 6;
  const int quad = lane >> 4, col16 = lane & 15;
  const int wrow = (w >> 2) << 7, wcol = (w & 3) << 6;
  if (!is_vt) {
    int isK = b >> 8, rem = b & 255;
    long r0 = (long)(rem >> 2) * 256, c0 = (long)(rem & 3) * 256;
    const float* bias = isK ? bk : bq;
    bf16* out = isK ? K : Q;
#pragma unroll
    for (int n = 0; n < 4; ++n) {
      int col = (int)c0 + wcol + (n >> 1) * 32 + (n & 1) * 16 + col16;
      float bb = bias[col];
#pragma unroll
      for (int m = 0; m < 8; ++m) {
        long rowb = r0 + wrow + (m >> 2) * 64 + (m & 3) * 16 + quad * 4;
#pragma unroll
        for (int r = 0; r < 4; ++r)
          out[(rowb + r) * 1024 + col] = (bf16)(acc[m][n][r] + bb);
      }
    }
  } else {
    int rem = b - 512;
    int z = rem >> 6;
    long r0 = (long)((rem >> 4) & 3) * 256, c0 = (long)(rem & 15) * 256;
    bf16* out = Vt + (long)z * 4194304;
#pragma unroll
    for (int m = 0; m < 8; ++m) {
      long rowb = r0 + wrow + (m >> 2) * 64 + (m & 3) * 16 + quad * 4;
      float bb[4];
#pragma unroll
      for (int r = 0; r < 4; ++r) bb[r] = bv[rowb + r];
#pragma unroll
      for (int n = 0; n < 4; ++n) {
        int col = (int)c0 + wcol + (n >> 1) * 32 + (n & 1) * 16 + col16;
#pragma unroll
        for (int r = 0; r < 4; ++r)
          out[(rowb + r) * 4096 + col] = (bf16)(acc[m][n][r] + bb[r]);
      }
    }
  }
}

// P~ = exp(Q.K^T/32) on 256x256 lower-tri tiles via the 8-phase core.
// 136 tiles x 4z = 544 blocks x 512 threads. Epilogue scatters the four
// 128x128 quadrants into the existing triangular S layout (the above-diag
// quadrant of diag tiles has no storage and is skipped) and emits psum
// bit-identically to the old 128-tile kernel (same column-pair order).
__global__ __launch_bounds__(512, 2) void s_gemm(const bf16* __restrict__ Q,
                                                 const bf16* __restrict__ K,
                                                 bf16* __restrict__ S,
                                                 float* __restrict__ psum) {
  __shared__ __align__(16) bf16 lds[4][16384];  // 128 KiB staging
  __shared__ float sred[8][128];
  const int tid = (int)threadIdx.x;
  const CC c = mk_cc(tid);
  int b0i = (int)blockIdx.x;
  int b = (b0i & 7) * 68 + (b0i >> 3);  // bijective XCD swizzle (544 = 8*68)
  int z = b & 3, ti = b >> 2;
  int QT = tridec(ti);
  int KT = ti - QT * (QT + 1) / 2;
  const bf16* Ag = Q + (long)z * 4194304 + (long)QT * 262144;
  const bf16* Bg = K + (long)z * 4194304 + (long)KT * 262144;
  f32x4 acc[8][4];
  zero8x4(acc);
  gemm256_core<16>(Ag, Bg, lds[0], lds[1], lds[2], lds[3], c, acc);

  // epilogue: exp, mask, store S quadrant, row-sums -> psum
  const int lane = tid & 63, w = tid >> 6;
  const int quad = lane >> 4, col16 = lane & 15;
  const int rh = w >> 2, ch = (w & 3) >> 1;
  const int wcol64 = (w & 1) << 6;  // col offset within the 128-quadrant
  const bool diag = (QT == KT);
  const bool skip = diag && (rh == 0) && (ch == 1);
  const bool mask = diag && (rh == ch);
  const int qt128 = 2 * QT + rh, kt128 = 2 * KT + ch;
  bf16* st = S + ((long)z * 528 + (long)(qt128 * (qt128 + 1) / 2 + kt128)) * 16384;
  float rs[8][4];
#pragma unroll
  for (int m = 0; m < 8; ++m)
#pragma unroll
    for (int r = 0; r < 4; ++r) rs[m][r] = 0.f;
#pragma unroll
  for (int m = 0; m < 8; ++m) {
    int row_l = (m >> 2) * 64 + (m & 3) * 16 + quad * 4;  // 0..127 within quadrant
#pragma unroll
    for (int n = 0; n < 4; ++n) {
      int col_l = wcol64 + (n >> 1) * 32 + (n & 1) * 16 + col16;  // 0..127
#pragma unroll
      for (int r = 0; r < 4; ++r) {
        float p = exp2f(acc[m][n][r] * (0.03125f * LOG2E));
        if (mask && col_l > row_l + r) p = 0.0f;
        bf16 h = (bf16)p;
        if (!skip) st[(row_l + r) * 128 + col_l] = h;
        rs[m][r] += (float)h;  // sum rounded values, n-ascending (old j-order)
      }
    }
  }
#pragma unroll
  for (int m = 0; m < 8; ++m)
#pragma unroll
    for (int r = 0; r < 4; ++r)
#pragma unroll
      for (int msk = 1; msk <= 8; msk <<= 1)
        rs[m][r] += __shfl_xor(rs[m][r], msk);
  if (col16 == 0) {
#pragma unroll
    for (int m = 0; m < 8; ++m)
#pragma unroll
      for (int r = 0; r < 4; ++r)
        sred[w][(m >> 2) * 64 + (m & 3) * 16 + quad * 4 + r] = rs[m][r];
  }
  __syncthreads();
  {
    int rh2 = (tid >> 7) & 1, row_l = tid & 127, ch2 = tid >> 8;
    int base = rh2 * 4 + ch2 * 2;
    psum[((long)z * 4096 + (long)QT * 256 + rh2 * 128 + row_l) * 32 + 2 * KT + ch2] =
        sred[base][row_l] + sred[base + 1][row_l];
  }
}

// linv[row] = 1 / sum over causal k-tiles of psum
__global__ __launch_bounds__(256) void inv_sums(const float* __restrict__ psum,
                                                float* __restrict__ linv) {
  long i = (long)blockIdx.x * 256 + threadIdx.x;  // 16384 rows
  int q = (int)(i & 4095);
  int nt = (q >> 7) + 1;
  const float* ps = psum + i * 32;
  float l = 0.f;
  for (int t = 0; t < nt; ++t) l += ps[t];
  linv[i] = 1.0f / l;
}

// O[q][e] = (sum_k P~[q][k] * Vt[e][k]) * linv[q], causal k bound; fp32 out.
// 1D grid: z bits 0-1, et bits 2-4, q0 bits 5-7, gen bits 8-9.
// qt = {q0, 15-q0, 16+q0, 31-q0} by gen -> co-resident set on each CU
// (blocks c, c+256, c+512, c+768) sums to exactly 66 k-tiles.
__global__ __launch_bounds__(256) void o_gemm(const bf16* __restrict__ S,
                                              const bf16* __restrict__ Vt,
                                              const float* __restrict__ linv,
                                              float* __restrict__ out) {
  __shared__ __align__(16) bf16 sA[2][128 * 32], sB[2][128 * 32];
  Ctx c = mk_ctx();
  int b = (int)blockIdx.x;
  int z = b & 3, et = (b >> 2) & 7, q0i = (b >> 5) & 7, gen = b >> 8;
  int qt = (gen == 0) ? q0i : (gen == 1) ? 15 - q0i
         : (gen == 2) ? 16 + q0i : 31 - q0i;
  long q0 = (long)qt * 128, e0 = (long)et * 128;
  const bf16* Bb = Vt + (long)z * 4194304 + e0 * 4096;
  long tribase = ((long)z * 528 + (long)qt * (qt + 1) / 2) * 16384;
  f32x4 acc[4][4]; zero_acc(acc);
  int kend = (qt + 1) * 128;
  for (int k = 0; k < kend; k += 64) {
    const bf16* Ab = S + tribase + (long)(k >> 7) * 16384 + (k & 127);
    stage_tile(Ab,      128, sA[0], c.tid);
    stage_tile(Ab + 32, 128, sA[1], c.tid);
    stage_tile(Bb + k,      4096, sB[0], c.tid);
    stage_tile(Bb + k + 32, 4096, sB[1], c.tid);
    __syncthreads();
    mfma_step(sA[0], sB[0], c, acc);
    mfma_step(sA[1], sB[1], c, acc);
    __syncthreads();
  }
  long zq = (long)z * 4096 + q0;
#pragma unroll
  for (int i = 0; i < 4; ++i) {
    int rowb = c.wr + i * 16 + c.quad * 4;
    float li[4];
#pragma unroll
    for (int r = 0; r < 4; ++r) li[r] = linv[zq + rowb + r];
#pragma unroll
    for (int j = 0; j < 4; ++j) {
      int col = c.wc + j * 16 + c.col16;
#pragma unroll
      for (int r = 0; r < 4; ++r)
        out[(zq + rowb + r) * 1024 + e0 + col] = acc[i][j][r] * li[r];
    }
  }
}

// ---------------- launcher ----------------
extern "C" void kernel_launch(void* const* d_in, const int* in_sizes, int n_in,
                              void* d_out, int out_size, void* d_ws, size_t ws_size,
                              hipStream_t stream) {
  (void)in_sizes; (void)n_in; (void)out_size; (void)ws_size;
  const float* x  = (const float*)d_in[0];
  const float* Wq = (const float*)d_in[1];
  const float* bq = (const float*)d_in[2];
  const float* Wk = (const float*)d_in[3];
  const float* bk = (const float*)d_in[4];
  const float* Wv = (const float*)d_in[5];
  const float* bv = (const float*)d_in[6];

  char* ws = (char*)d_ws;
  bf16*  xb   = (bf16*)(ws + OFF_XB);
  bf16*  wqb  = (bf16*)(ws + OFF_WQB);
  bf16*  wkb  = (bf16*)(ws + OFF_WKB);
  bf16*  wvb  = (bf16*)(ws + OFF_WVB);
  bf16*  Qb   = (bf16*)(ws + OFF_Q);
  bf16*  Kb   = (bf16*)(ws + OFF_K);
  bf16*  Vtb  = (bf16*)(ws + OFF_VT);
  bf16*  Sb   = (bf16*)(ws + OFF_S);
  float* psum = (float*)(ws + OFF_PSUM);
  float* linv = (float*)(ws + OFF_LINV);

  cvt_all<<<9728, 256, 0, stream>>>(x, Wq, Wk, Wv, xb, wqb, wkb, wvb);
  qkv_gemm<<<768, 512, 0, stream>>>(xb, wqb, wkb, wvb, bq, bk, bv, Qb, Kb, Vtb);
  s_gemm<<<544, 512, 0, stream>>>(Qb, Kb, Sb, psum);
  inv_sums<<<64, 256, 0, stream>>>(psum, linv);
  o_gemm<<<1024, 256, 0, stream>>>(Sb, Vtb, linv, (float*)d_out);
}